// Round 12
// baseline (151.847 us; speedup 1.0000x reference)
//
#include <hip/hip_runtime.h>

#define D 512
#define NH 8
#define DH 64
#define CCTX 64
#define LN_EPS 1e-5f
#define NCHAIN 128          // blocks running the chain
#define NGRID  2048         // blocks for warm/final
#define CHF    49           // rows per block: ceil(100000/2048)

// workspace float offsets
#define WS_T     0        // 8
#define WS_M     512      // 4096
#define WS_CTX   5120     // 64*512
#define WS_CBAR  40960    // 4096
#define WS_O     45056    // 512
#define WS_OUT1  45568    // 512
#define WS_V     46080    // 512
#define WS_ATTN2 46592    // 512
#define WS_FLAGS 47104    // 128 unsigned (per-block barrier flags)

typedef float f4v __attribute__((ext_vector_type(4)));

__device__ __forceinline__ float waveReduceSum(float v) {
#pragma unroll
    for (int off = 32; off > 0; off >>= 1) v += __shfl_xor(v, off);
    return v;
}

// Contention-free barrier among the 128 chain blocks. RELAXED polls + one
// acquire fence on exit (r7-validated: no per-poll cache invalidation).
__device__ __forceinline__ void barFlags(unsigned* flags, unsigned phase) {
    __syncthreads();
    if (threadIdx.x == 0)
        __hip_atomic_store(&flags[blockIdx.x], phase, __ATOMIC_RELEASE,
                           __HIP_MEMORY_SCOPE_AGENT);
    if (threadIdx.x < 64) {
        while (true) {
            unsigned f0 = __hip_atomic_load(&flags[threadIdx.x],
                                            __ATOMIC_RELAXED, __HIP_MEMORY_SCOPE_AGENT);
            unsigned f1 = __hip_atomic_load(&flags[64 + threadIdx.x],
                                            __ATOMIC_RELAXED, __HIP_MEMORY_SCOPE_AGENT);
            if (__all(f0 >= phase && f1 >= phase)) break;
            __builtin_amdgcn_s_sleep(2);
        }
        __builtin_amdgcn_fence(__ATOMIC_ACQUIRE, "agent");
    }
    __syncthreads();
}

__global__ __launch_bounds__(128) void k_init(unsigned* flags) {
    flags[threadIdx.x] = 0u;
}

// wave-per-row matvec: y[r] = W[r,:] . x(+head offset) + b[r]
__device__ __forceinline__ void matvec_rows(
    const float* __restrict__ W, const float* __restrict__ x,
    const float* __restrict__ b, float* __restrict__ y, int headStride)
{
    int wib = threadIdx.x >> 6, lane = threadIdx.x & 63;
    int r = blockIdx.x * 4 + wib;                    // 0..511
    const float* xr = x + (r >> 6) * headStride;
    const float* Wr = W + (size_t)r * D;
    float4 w0 = *(const float4*)(Wr + lane * 4);
    float4 w1 = *(const float4*)(Wr + 256 + lane * 4);
    float4 x0 = *(const float4*)(xr + lane * 4);
    float4 x1 = *(const float4*)(xr + 256 + lane * 4);
    float s = w0.x*x0.x + w0.y*x0.y + w0.z*x0.z + w0.w*x0.w
            + w1.x*x1.x + w1.y*x1.y + w1.z*x1.z + w1.w*x1.w;
    s = waveReduceSum(s);
    if (lane == 0) y[r] = s + b[r];
}

// The small chain ALONE: 128 blocks x 256 threads, 5 barriers (R8 structure).
__global__ __launch_bounds__(256) void k_chain(
    const float* __restrict__ Hm,   const float* __restrict__ path,
    const float* __restrict__ Win1, const float* __restrict__ bin1,
    const float* __restrict__ Wout1,const float* __restrict__ bout1,
    const float* __restrict__ Win2, const float* __restrict__ bin2,
    const float* __restrict__ Wout2,const float* __restrict__ bout2,
    const float* __restrict__ ln1g, const float* __restrict__ ln1b,
    const int* __restrict__ ids,    float* __restrict__ ws)
{
    __shared__ __align__(16) float smem[532];
    unsigned* flags = (unsigned*)(ws + WS_FLAGS);
    const int B = blockIdx.x, tid = threadIdx.x;
    const int wib = tid >> 6, lane = tid & 63;

    // ---- P0: gather ctx (blocks 0..63) ; qh+m+t per half-head (blocks 64..79) ----
    if (B < 64) {
        if (tid < 128) {
            int id = ids[B];
            float4 v = *(const float4*)(Hm + (size_t)id * D + tid * 4);
            *(float4*)(ws + WS_CTX + B * D + tid * 4) = v;
        }
    } else if (B < 80) {
        int bm = B - 64;                 // 0..15
        int h = bm >> 1, half = bm & 1;
        float* qh_lds = smem;            // 64 floats: qh for head h
        {
            int rr = tid >> 2, p = tid & 3;
            const float* wrow = Win1 + (size_t)(h * DH + rr) * D + p * 128;
            const float* xrow = path + p * 128;
            float s = 0.f;
#pragma unroll 8
            for (int k = 0; k < 32; ++k) {
                float4 a = *(const float4*)(wrow + k * 4);
                float4 c = *(const float4*)(xrow + k * 4);
                s += a.x*c.x + a.y*c.y + a.z*c.z + a.w*c.w;
            }
            s += __shfl_xor(s, 1);
            s += __shfl_xor(s, 2);
            if (p == 0) qh_lds[rr] = s + bin1[h * DH + rr];
        }
        __syncthreads();
        {
            int c = half * 256 + tid;
            const float* Wk = Win1 + (size_t)D * D;
            float acc = 0.f;
#pragma unroll 8
            for (int d = 0; d < DH; ++d)
                acc += Wk[(size_t)(h * DH + d) * D + c] * qh_lds[d];
            ws[WS_M + h * D + c] = acc;
        }
        if (half == 0 && tid == 0) {
            float tt = 0.f;
            for (int d = 0; d < DH; ++d) tt += bin1[D + h * DH + d] * qh_lds[d];
            ws[WS_T + h] = tt;
        }
    }
    barFlags(flags, 1);

    // ---- P1: blocks 0..7 (one per head) — scores -> softmax -> cbar_h ----
    if (B < NH) {
        const int h = B;
        float* s_lds = smem;          // 64 scores
        float* w_lds = smem + 64;     // 64 weights
        {
            int j = tid >> 2, p = tid & 3;
            const float* cr = ws + WS_CTX + j * D + p * 128;
            const float* mr = ws + WS_M + h * D + p * 128;
            float s = 0.f;
#pragma unroll 8
            for (int c4 = 0; c4 < 32; ++c4) {
                float4 a = *(const float4*)(cr + c4 * 4);
                float4 b = *(const float4*)(mr + c4 * 4);
                s += a.x*b.x + a.y*b.y + a.z*b.z + a.w*b.w;
            }
            s += __shfl_xor(s, 1);
            s += __shfl_xor(s, 2);
            if (p == 0) s_lds[j] = (s + ws[WS_T + h]) * 0.125f;
        }
        __syncthreads();
        if (wib == 0) {
            float sc = s_lds[lane];
            float mx = sc;
#pragma unroll
            for (int off = 32; off > 0; off >>= 1) mx = fmaxf(mx, __shfl_xor(mx, off));
            float e = __expf(sc - mx);
            float sum = waveReduceSum(e);
            w_lds[lane] = e / sum;
        }
        __syncthreads();
        for (int c = tid; c < D; c += 256) {
            float acc = 0.f;
#pragma unroll 8
            for (int j = 0; j < CCTX; ++j) acc += w_lds[j] * ws[WS_CTX + j * D + c];
            ws[WS_CBAR + h * D + c] = acc;
        }
    }
    barFlags(flags, 2);

    // ---- P2: o = Wv @ cbar + bv (per-head x) ----
    matvec_rows(Win1 + 2 * (size_t)D * D, ws + WS_CBAR, bin1 + 2 * D, ws + WS_O, D);
    barFlags(flags, 3);

    // ---- P3: out1 = Wout1 @ o + bout1 ----
    matvec_rows(Wout1, ws + WS_O, bout1, ws + WS_OUT1, 0);
    barFlags(flags, 4);

    // ---- P4: xs = LN(out1 + path)*g1+b1, v = Wv2 @ xs + bv2 ----
    {
        float* xs  = smem;          // 512
        float* red = smem + 520;    // 8
        float a0 = ws[WS_OUT1 + tid * 2]     + path[tid * 2];
        float a1 = ws[WS_OUT1 + tid * 2 + 1] + path[tid * 2 + 1];
        float s  = a0 + a1;
        float s2 = a0 * a0 + a1 * a1;
        s  = waveReduceSum(s);
        s2 = waveReduceSum(s2);
        if (lane == 0) { red[wib] = s; red[4 + wib] = s2; }
        __syncthreads();
        float st  = red[0] + red[1] + red[2] + red[3];
        float s2t = red[4] + red[5] + red[6] + red[7];
        float mu   = st * (1.f / D);
        float var  = s2t * (1.f / D) - mu * mu;
        float rinv = rsqrtf(var + LN_EPS);
        xs[tid * 2]     = (a0 - mu) * rinv * ln1g[tid * 2]     + ln1b[tid * 2];
        xs[tid * 2 + 1] = (a1 - mu) * rinv * ln1g[tid * 2 + 1] + ln1b[tid * 2 + 1];
        __syncthreads();
        matvec_rows(Win2 + 2 * (size_t)D * D, xs, bin2 + 2 * D, ws + WS_V, 0);
    }
    barFlags(flags, 5);

    // ---- P5: attn2 = Wout2 @ v + bout2 ----
    matvec_rows(Wout2, ws + WS_V, bout2, ws + WS_ATTN2, 0);
}

// Pure L3 warm: each block stream-reads the SAME 49-row chunk its k_final
// twin will process. Uniform read-only phase at full BW; no sync, no writes.
__global__ __launch_bounds__(256) void k_warm(
    const float* __restrict__ Hm, int N)
{
    int s0r = blockIdx.x * CHF;
    int e0r = s0r + CHF; if (e0r > N) e0r = N;
    if (s0r >= e0r) return;
    const float4* H4 = (const float4*)Hm;
    float4 acc = {0.f, 0.f, 0.f, 0.f};
    int lo = s0r * 128 + threadIdx.x, hi = e0r * 128;
#pragma unroll 4
    for (int i = lo; i < hi; i += 256) {
        float4 v = H4[i];
        acc.x += v.x; acc.y += v.y; acc.z += v.z; acc.w += v.w;
    }
    asm volatile("" :: "v"(acc.x), "v"(acc.y), "v"(acc.z), "v"(acc.w));
}

// H_cond[i,:] = LN(attn2 + H[i,:]) * g + b — contiguous 49-row chunk per
// block (L3-warm), ILP-2 reduce, NT stores (L3-absorbed).
__global__ __launch_bounds__(256) void k_final(
    const float* __restrict__ Hm, const float* __restrict__ attn2,
    const float* __restrict__ g, const float* __restrict__ b,
    float* __restrict__ out, int N)
{
    const int lane = threadIdx.x & 63;
    const int wib  = threadIdx.x >> 6;
    const int c0 = lane * 4, c1 = 256 + lane * 4;
    float4 a0 = *(const float4*)(attn2 + c0), a1 = *(const float4*)(attn2 + c1);
    float4 g0 = *(const float4*)(g + c0),     g1 = *(const float4*)(g + c1);
    float4 b0 = *(const float4*)(b + c0),     b1 = *(const float4*)(b + c1);
    const float4* H4 = (const float4*)Hm;
    float4*       O4 = (float4*)out;
    const float4  z4 = {0.f, 0.f, 0.f, 0.f};
    int s0r = blockIdx.x * CHF;
    int e0r = s0r + CHF; if (e0r > N) e0r = N;

    for (int row = s0r + wib * 2; row < e0r; row += 8) {
        bool hasB = (row + 1) < e0r;
        size_t i0 = (size_t)row * 128 + lane;
        float4 xa0 = H4[i0], xa1 = H4[i0 + 64];
        float4 xb0 = hasB ? H4[i0 + 128] : z4;
        float4 xb1 = hasB ? H4[i0 + 192] : z4;

        float4 pa0, pa1, pb0, pb1;
        pa0.x = xa0.x + a0.x; pa0.y = xa0.y + a0.y; pa0.z = xa0.z + a0.z; pa0.w = xa0.w + a0.w;
        pa1.x = xa1.x + a1.x; pa1.y = xa1.y + a1.y; pa1.z = xa1.z + a1.z; pa1.w = xa1.w + a1.w;
        pb0.x = xb0.x + a0.x; pb0.y = xb0.y + a0.y; pb0.z = xb0.z + a0.z; pb0.w = xb0.w + a0.w;
        pb1.x = xb1.x + a1.x; pb1.y = xb1.y + a1.y; pb1.z = xb1.z + a1.z; pb1.w = xb1.w + a1.w;

        float sA  = pa0.x + pa0.y + pa0.z + pa0.w + pa1.x + pa1.y + pa1.z + pa1.w;
        float s2A = pa0.x*pa0.x + pa0.y*pa0.y + pa0.z*pa0.z + pa0.w*pa0.w
                  + pa1.x*pa1.x + pa1.y*pa1.y + pa1.z*pa1.z + pa1.w*pa1.w;
        float sB  = pb0.x + pb0.y + pb0.z + pb0.w + pb1.x + pb1.y + pb1.z + pb1.w;
        float s2B = pb0.x*pb0.x + pb0.y*pb0.y + pb0.z*pb0.z + pb0.w*pb0.w
                  + pb1.x*pb1.x + pb1.y*pb1.y + pb1.z*pb1.z + pb1.w*pb1.w;

#pragma unroll
        for (int off = 32; off > 0; off >>= 1) {
            sA  += __shfl_xor(sA,  off);
            s2A += __shfl_xor(s2A, off);
            sB  += __shfl_xor(sB,  off);
            s2B += __shfl_xor(s2B, off);
        }

        float muA   = sA * (1.f / D);
        float varA  = s2A * (1.f / D) - muA * muA;
        float rinvA = rsqrtf(varA + LN_EPS);
        float muB   = sB * (1.f / D);
        float varB  = s2B * (1.f / D) - muB * muB;
        float rinvB = rsqrtf(varB + LN_EPS);

        f4v y;
        y.x = (pa0.x - muA) * rinvA * g0.x + b0.x;
        y.y = (pa0.y - muA) * rinvA * g0.y + b0.y;
        y.z = (pa0.z - muA) * rinvA * g0.z + b0.z;
        y.w = (pa0.w - muA) * rinvA * g0.w + b0.w;
        __builtin_nontemporal_store(y, (f4v*)(O4 + i0));
        y.x = (pa1.x - muA) * rinvA * g1.x + b1.x;
        y.y = (pa1.y - muA) * rinvA * g1.y + b1.y;
        y.z = (pa1.z - muA) * rinvA * g1.z + b1.z;
        y.w = (pa1.w - muA) * rinvA * g1.w + b1.w;
        __builtin_nontemporal_store(y, (f4v*)(O4 + i0 + 64));
        if (hasB) {
            y.x = (pb0.x - muB) * rinvB * g0.x + b0.x;
            y.y = (pb0.y - muB) * rinvB * g0.y + b0.y;
            y.z = (pb0.z - muB) * rinvB * g0.z + b0.z;
            y.w = (pb0.w - muB) * rinvB * g0.w + b0.w;
            __builtin_nontemporal_store(y, (f4v*)(O4 + i0 + 128));
            y.x = (pb1.x - muB) * rinvB * g1.x + b1.x;
            y.y = (pb1.y - muB) * rinvB * g1.y + b1.y;
            y.z = (pb1.z - muB) * rinvB * g1.z + b1.z;
            y.w = (pb1.w - muB) * rinvB * g1.w + b1.w;
            __builtin_nontemporal_store(y, (f4v*)(O4 + i0 + 192));
        }
    }
}

extern "C" void kernel_launch(void* const* d_in, const int* in_sizes, int n_in,
                              void* d_out, int out_size, void* d_ws, size_t ws_size,
                              hipStream_t stream)
{
    const float* Hm    = (const float*)d_in[0];
    const float* path  = (const float*)d_in[1];
    const float* Win1  = (const float*)d_in[2];
    const float* bin1  = (const float*)d_in[3];
    const float* Wout1 = (const float*)d_in[4];
    const float* bout1 = (const float*)d_in[5];
    const float* Win2  = (const float*)d_in[6];
    const float* bin2  = (const float*)d_in[7];
    const float* Wout2 = (const float*)d_in[8];
    const float* bout2 = (const float*)d_in[9];
    const float* ln1g  = (const float*)d_in[10];
    const float* ln1b  = (const float*)d_in[11];
    const float* ln2g  = (const float*)d_in[12];
    const float* ln2b  = (const float*)d_in[13];
    // d_in[14] = edge_index — unused by the reference
    const int*   ids   = (const int*)d_in[15];

    float* ws  = (float*)d_ws;
    float* out = (float*)d_out;
    const int N = in_sizes[0] / D;

    k_init<<<1, 128, 0, stream>>>((unsigned*)(ws + WS_FLAGS));
    k_chain<<<NCHAIN, 256, 0, stream>>>(Hm, path, Win1, bin1, Wout1, bout1,
                                        Win2, bin2, Wout2, bout2, ln1g, ln1b,
                                        ids, ws);
    k_warm<<<NGRID, 256, 0, stream>>>(Hm, N);
    k_final<<<NGRID, 256, 0, stream>>>(Hm, ws + WS_ATTN2, ln2g, ln2b, out, N);
}

// Round 13
// 132.804 us; speedup vs baseline: 1.1434x; 1.1434x over previous
//
#include <hip/hip_runtime.h>

#define D 512
#define NH 8
#define DH 64
#define CCTX 64
#define LN_EPS 1e-5f
#define NCHAIN 128          // blocks running the chain
#define FROWS  25           // rows per final block (100000 = 4000 * 25)

// workspace float offsets
#define WS_T     0        // 8
#define WS_M     512      // 4096
#define WS_CTX   5120     // 64*512
#define WS_CBAR  40960    // 4096
#define WS_O     45056    // 512
#define WS_OUT1  45568    // 512
#define WS_V     46080    // 512
#define WS_ATTN2 46592    // 512
#define WS_FLAGS 47104    // 128 unsigned (per-block barrier flags)

typedef float f4v __attribute__((ext_vector_type(4)));

__device__ __forceinline__ float waveReduceSum(float v) {
#pragma unroll
    for (int off = 32; off > 0; off >>= 1) v += __shfl_xor(v, off);
    return v;
}

// Contention-free barrier among the 128 chain blocks. RELAXED polls + one
// acquire fence on exit (r7-validated: no per-poll cache invalidation).
__device__ __forceinline__ void barFlags(unsigned* flags, unsigned phase) {
    __syncthreads();
    if (threadIdx.x == 0)
        __hip_atomic_store(&flags[blockIdx.x], phase, __ATOMIC_RELEASE,
                           __HIP_MEMORY_SCOPE_AGENT);
    if (threadIdx.x < 64) {
        while (true) {
            unsigned f0 = __hip_atomic_load(&flags[threadIdx.x],
                                            __ATOMIC_RELAXED, __HIP_MEMORY_SCOPE_AGENT);
            unsigned f1 = __hip_atomic_load(&flags[64 + threadIdx.x],
                                            __ATOMIC_RELAXED, __HIP_MEMORY_SCOPE_AGENT);
            if (__all(f0 >= phase && f1 >= phase)) break;
            __builtin_amdgcn_s_sleep(2);
        }
        __builtin_amdgcn_fence(__ATOMIC_ACQUIRE, "agent");
    }
    __syncthreads();
}

__global__ __launch_bounds__(128) void k_init(unsigned* flags) {
    flags[threadIdx.x] = 0u;
}

// wave-per-row matvec: y[r] = W[r,:] . x(+head offset) + b[r]
__device__ __forceinline__ void matvec_rows(
    const float* __restrict__ W, const float* __restrict__ x,
    const float* __restrict__ b, float* __restrict__ y, int headStride)
{
    int wib = threadIdx.x >> 6, lane = threadIdx.x & 63;
    int r = blockIdx.x * 4 + wib;                    // 0..511
    const float* xr = x + (r >> 6) * headStride;
    const float* Wr = W + (size_t)r * D;
    float4 w0 = *(const float4*)(Wr + lane * 4);
    float4 w1 = *(const float4*)(Wr + 256 + lane * 4);
    float4 x0 = *(const float4*)(xr + lane * 4);
    float4 x1 = *(const float4*)(xr + 256 + lane * 4);
    float s = w0.x*x0.x + w0.y*x0.y + w0.z*x0.z + w0.w*x0.w
            + w1.x*x1.x + w1.y*x1.y + w1.z*x1.z + w1.w*x1.w;
    s = waveReduceSum(s);
    if (lane == 0) y[r] = s + b[r];
}

// The small chain ALONE: 128 blocks x 256 threads, 5 barriers (R8 structure).
__global__ __launch_bounds__(256) void k_chain(
    const float* __restrict__ Hm,   const float* __restrict__ path,
    const float* __restrict__ Win1, const float* __restrict__ bin1,
    const float* __restrict__ Wout1,const float* __restrict__ bout1,
    const float* __restrict__ Win2, const float* __restrict__ bin2,
    const float* __restrict__ Wout2,const float* __restrict__ bout2,
    const float* __restrict__ ln1g, const float* __restrict__ ln1b,
    const int* __restrict__ ids,    float* __restrict__ ws)
{
    __shared__ __align__(16) float smem[532];
    unsigned* flags = (unsigned*)(ws + WS_FLAGS);
    const int B = blockIdx.x, tid = threadIdx.x;
    const int wib = tid >> 6, lane = tid & 63;

    // ---- P0: gather ctx (blocks 0..63) ; qh+m+t per half-head (blocks 64..79) ----
    if (B < 64) {
        if (tid < 128) {
            int id = ids[B];
            float4 v = *(const float4*)(Hm + (size_t)id * D + tid * 4);
            *(float4*)(ws + WS_CTX + B * D + tid * 4) = v;
        }
    } else if (B < 80) {
        int bm = B - 64;                 // 0..15
        int h = bm >> 1, half = bm & 1;
        float* qh_lds = smem;            // 64 floats: qh for head h
        {
            int rr = tid >> 2, p = tid & 3;
            const float* wrow = Win1 + (size_t)(h * DH + rr) * D + p * 128;
            const float* xrow = path + p * 128;
            float s = 0.f;
#pragma unroll 8
            for (int k = 0; k < 32; ++k) {
                float4 a = *(const float4*)(wrow + k * 4);
                float4 c = *(const float4*)(xrow + k * 4);
                s += a.x*c.x + a.y*c.y + a.z*c.z + a.w*c.w;
            }
            s += __shfl_xor(s, 1);
            s += __shfl_xor(s, 2);
            if (p == 0) qh_lds[rr] = s + bin1[h * DH + rr];
        }
        __syncthreads();
        {
            int c = half * 256 + tid;
            const float* Wk = Win1 + (size_t)D * D;
            float acc = 0.f;
#pragma unroll 8
            for (int d = 0; d < DH; ++d)
                acc += Wk[(size_t)(h * DH + d) * D + c] * qh_lds[d];
            ws[WS_M + h * D + c] = acc;
        }
        if (half == 0 && tid == 0) {
            float tt = 0.f;
            for (int d = 0; d < DH; ++d) tt += bin1[D + h * DH + d] * qh_lds[d];
            ws[WS_T + h] = tt;
        }
    }
    barFlags(flags, 1);

    // ---- P1: blocks 0..7 (one per head) — scores -> softmax -> cbar_h ----
    if (B < NH) {
        const int h = B;
        float* s_lds = smem;          // 64 scores
        float* w_lds = smem + 64;     // 64 weights
        {
            int j = tid >> 2, p = tid & 3;
            const float* cr = ws + WS_CTX + j * D + p * 128;
            const float* mr = ws + WS_M + h * D + p * 128;
            float s = 0.f;
#pragma unroll 8
            for (int c4 = 0; c4 < 32; ++c4) {
                float4 a = *(const float4*)(cr + c4 * 4);
                float4 b = *(const float4*)(mr + c4 * 4);
                s += a.x*b.x + a.y*b.y + a.z*b.z + a.w*b.w;
            }
            s += __shfl_xor(s, 1);
            s += __shfl_xor(s, 2);
            if (p == 0) s_lds[j] = (s + ws[WS_T + h]) * 0.125f;
        }
        __syncthreads();
        if (wib == 0) {
            float sc = s_lds[lane];
            float mx = sc;
#pragma unroll
            for (int off = 32; off > 0; off >>= 1) mx = fmaxf(mx, __shfl_xor(mx, off));
            float e = __expf(sc - mx);
            float sum = waveReduceSum(e);
            w_lds[lane] = e / sum;
        }
        __syncthreads();
        for (int c = tid; c < D; c += 256) {
            float acc = 0.f;
#pragma unroll 8
            for (int j = 0; j < CCTX; ++j) acc += w_lds[j] * ws[WS_CTX + j * D + c];
            ws[WS_CBAR + h * D + c] = acc;
        }
    }
    barFlags(flags, 2);

    // ---- P2: o = Wv @ cbar + bv (per-head x) ----
    matvec_rows(Win1 + 2 * (size_t)D * D, ws + WS_CBAR, bin1 + 2 * D, ws + WS_O, D);
    barFlags(flags, 3);

    // ---- P3: out1 = Wout1 @ o + bout1 ----
    matvec_rows(Wout1, ws + WS_O, bout1, ws + WS_OUT1, 0);
    barFlags(flags, 4);

    // ---- P4: xs = LN(out1 + path)*g1+b1, v = Wv2 @ xs + bv2 ----
    {
        float* xs  = smem;          // 512
        float* red = smem + 520;    // 8
        float a0 = ws[WS_OUT1 + tid * 2]     + path[tid * 2];
        float a1 = ws[WS_OUT1 + tid * 2 + 1] + path[tid * 2 + 1];
        float s  = a0 + a1;
        float s2 = a0 * a0 + a1 * a1;
        s  = waveReduceSum(s);
        s2 = waveReduceSum(s2);
        if (lane == 0) { red[wib] = s; red[4 + wib] = s2; }
        __syncthreads();
        float st  = red[0] + red[1] + red[2] + red[3];
        float s2t = red[4] + red[5] + red[6] + red[7];
        float mu   = st * (1.f / D);
        float var  = s2t * (1.f / D) - mu * mu;
        float rinv = rsqrtf(var + LN_EPS);
        xs[tid * 2]     = (a0 - mu) * rinv * ln1g[tid * 2]     + ln1b[tid * 2];
        xs[tid * 2 + 1] = (a1 - mu) * rinv * ln1g[tid * 2 + 1] + ln1b[tid * 2 + 1];
        __syncthreads();
        matvec_rows(Win2 + 2 * (size_t)D * D, xs, bin2 + 2 * D, ws + WS_V, 0);
    }
    barFlags(flags, 5);

    // ---- P5: attn2 = Wout2 @ v + bout2 ----
    matvec_rows(Wout2, ws + WS_V, bout2, ws + WS_ATTN2, 0);
}

// H_cond[i,:] = LN(attn2 + H[i,:]) * g + b — LDS-staged three-phase:
//  P1: coalesced bulk copy H chunk -> LDS (pure read stream, copy-like)
//  P2: per-wave row reduce from LDS -> mu/rinv (zero HBM traffic)
//  P3: streaming transform + NT store (pure write stream)
// 25 rows x 2KB = 50KB LDS -> 3 blocks/CU, 12 waves/CU.
__global__ __launch_bounds__(256) void k_final(
    const float* __restrict__ Hm, const float* __restrict__ attn2,
    const float* __restrict__ g, const float* __restrict__ b,
    float* __restrict__ out, int N)
{
    __shared__ __align__(16) float tile[FROWS * D];   // 51200 B
    __shared__ float murinv[FROWS * 2];
    const int tid  = threadIdx.x;
    const int lane = tid & 63, wib = tid >> 6;
    const int rstart = blockIdx.x * FROWS;
    const int nrows  = (rstart + FROWS <= N) ? FROWS : (N - rstart);
    if (nrows <= 0) return;
    const int nf4 = nrows * (D / 4);                  // float4 count in chunk

    const float4* H4 = (const float4*)Hm;
    float4*       O4 = (float4*)out;
    float4*       T4 = (float4*)tile;
    const size_t  base4 = (size_t)rstart * (D / 4);

    // per-thread fixed column data
    const int col4 = tid & 127;                       // constant across iters
    float4 av = ((const float4*)attn2)[col4];
    float4 gv = ((const float4*)g)[col4];
    float4 bv = ((const float4*)b)[col4];
    // per-lane row-reduce columns
    float4 a0 = ((const float4*)attn2)[lane];
    float4 a1 = ((const float4*)attn2)[64 + lane];

    // ---- P1: bulk copy H -> LDS (coalesced, no dependent compute) ----
#pragma unroll 4
    for (int i = tid; i < nf4; i += 256)
        T4[i] = H4[base4 + i];
    __syncthreads();

    // ---- P2: per-wave row reduce ----
    for (int r = wib; r < nrows; r += 4) {
        float4 x0 = T4[r * 128 + lane];
        float4 x1 = T4[r * 128 + 64 + lane];
        float e0x = x0.x + a0.x, e0y = x0.y + a0.y, e0z = x0.z + a0.z, e0w = x0.w + a0.w;
        float e1x = x1.x + a1.x, e1y = x1.y + a1.y, e1z = x1.z + a1.z, e1w = x1.w + a1.w;
        float s  = e0x + e0y + e0z + e0w + e1x + e1y + e1z + e1w;
        float s2 = e0x*e0x + e0y*e0y + e0z*e0z + e0w*e0w
                 + e1x*e1x + e1y*e1y + e1z*e1z + e1w*e1w;
#pragma unroll
        for (int off = 32; off > 0; off >>= 1) {
            s  += __shfl_xor(s,  off);
            s2 += __shfl_xor(s2, off);
        }
        float mu   = s * (1.f / D);
        float var  = s2 * (1.f / D) - mu * mu;
        float rinv = rsqrtf(var + LN_EPS);
        if (lane == 0) { murinv[r * 2] = mu; murinv[r * 2 + 1] = rinv; }
    }
    __syncthreads();

    // ---- P3: streaming transform + NT store (pure write stream) ----
#pragma unroll 4
    for (int i = tid; i < nf4; i += 256) {
        int r = i >> 7;
        float4 x   = T4[i];
        float mu   = murinv[r * 2];
        float rinv = murinv[r * 2 + 1];
        f4v y;
        y.x = (x.x + av.x - mu) * rinv * gv.x + bv.x;
        y.y = (x.y + av.y - mu) * rinv * gv.y + bv.y;
        y.z = (x.z + av.z - mu) * rinv * gv.z + bv.z;
        y.w = (x.w + av.w - mu) * rinv * gv.w + bv.w;
        __builtin_nontemporal_store(y, (f4v*)(O4 + base4 + i));
    }
}

extern "C" void kernel_launch(void* const* d_in, const int* in_sizes, int n_in,
                              void* d_out, int out_size, void* d_ws, size_t ws_size,
                              hipStream_t stream)
{
    const float* Hm    = (const float*)d_in[0];
    const float* path  = (const float*)d_in[1];
    const float* Win1  = (const float*)d_in[2];
    const float* bin1  = (const float*)d_in[3];
    const float* Wout1 = (const float*)d_in[4];
    const float* bout1 = (const float*)d_in[5];
    const float* Win2  = (const float*)d_in[6];
    const float* bin2  = (const float*)d_in[7];
    const float* Wout2 = (const float*)d_in[8];
    const float* bout2 = (const float*)d_in[9];
    const float* ln1g  = (const float*)d_in[10];
    const float* ln1b  = (const float*)d_in[11];
    const float* ln2g  = (const float*)d_in[12];
    const float* ln2b  = (const float*)d_in[13];
    // d_in[14] = edge_index — unused by the reference
    const int*   ids   = (const int*)d_in[15];

    float* ws  = (float*)d_ws;
    float* out = (float*)d_out;
    const int N = in_sizes[0] / D;
    const int FB = (N + FROWS - 1) / FROWS;           // 4000 for N=100000

    k_init<<<1, 128, 0, stream>>>((unsigned*)(ws + WS_FLAGS));
    k_chain<<<NCHAIN, 256, 0, stream>>>(Hm, path, Win1, bin1, Wout1, bout1,
                                        Win2, bin2, Wout2, bout2, ln1g, ln1b,
                                        ids, ws);
    k_final<<<FB, 256, 0, stream>>>(Hm, ws + WS_ATTN2, ln2g, ln2b, out, N);
}